// Round 10
// baseline (630.368 us; speedup 1.0000x reference)
//
#include <hip/hip_runtime.h>
#include <hip/hip_fp16.h>

// Problem constants (from reference setup_inputs)
constexpr int B  = 16;
constexpr int C  = 64;
constexpr int OH = 128;
constexpr int OW = 128;
constexpr int HW = OH * OW;                 // 16384 inputs per (b,c) plane
constexpr int K  = 4;
constexpr int P  = 4;
constexpr int TAPS = HW * K * P;            // 262144 static taps
constexpr int OUT_H = 256;
constexpr int OUT_W = 256;
constexpr int PLANE = OUT_H * OUT_W;        // 65536 outputs per (b,c) plane
constexpr int NQ = 4;                       // quarters (fallback path)
constexpr int QUARTER = PLANE / NQ;
constexpr int BLOCK = 512;
constexpr size_t TABLE_BYTES = (size_t)HW * K * 16;  // 1 MiB compact table (fallback)

constexpr int GW = 4;                       // windows per staging group
constexpr int NGROUP = PLANE / 64;          // 1024 64-slot schedule groups

// ---- V2 (grouped/interleaved) workspace, u32 slots ----
//   counts : PLANE
//   cursor : PLANE
//   sched  : PLANE   (out_id per sorted slot)
//   wbase  : PLANE   (per-output u32 write base into entries2)
//   gdesc  : 2048    (uint4_base | M<<24, 1024 used; uint4_base = rowbase*64)
//   entries2: E2CAP uint4 chunks, lane-interleaved per group
constexpr int E2CAP = 229376;               // row budget 3584 vs ~1.6K expected
constexpr size_t WS_V2_BYTES = ((size_t)PLANE * 4 + 2048) * 4 + (size_t)E2CAP * 16;

// ---- R7 (sorted+staged) workspace ----
constexpr int CHUNK_CAP = 114688;
constexpr size_t WS_SORT_BYTES = ((size_t)PLANE * 5) * 4 + (size_t)CHUNK_CAP * 16; // 3.0 MiB

static __device__ __forceinline__ float h2f(unsigned short u) {
    __half h; __builtin_memcpy(&h, &u, 2); return __half2float(h);
}

typedef _Float16 h2_t __attribute__((ext_vector_type(2)));
static __device__ __forceinline__ h2_t as_h2(unsigned u) {
    h2_t r; __builtin_memcpy(&r, &u, 4); return r;
}

// ================= shared pre-pass =================

__global__ __launch_bounds__(256) void hist_kernel(
    const int* __restrict__ sm, unsigned* __restrict__ counts)
{
    int r = blockIdx.x * 256 + threadIdx.x;
    if (r < TAPS) atomicAdd(&counts[sm[r]], 1u);
}

// ================= V2 pre-pass =================

__global__ __launch_bounds__(256) void zero_v2_kernel(
    unsigned* __restrict__ counts, unsigned* __restrict__ cursor,
    uint4* __restrict__ entries2)
{
    int r = blockIdx.x * 256 + threadIdx.x;
    if (r < PLANE) { counts[r] = 0u; cursor[r] = 0u; }
    if (r < E2CAP) entries2[r] = make_uint4(0u, 0u, 0u, 0u);
}

// Window-local counting sort by nch=ceil(counts/4), ascending.
constexpr int WNB = 32;
__global__ __launch_bounds__(256) void window_sort_v2_kernel(
    const unsigned* __restrict__ counts, unsigned* __restrict__ sched)
{
    __shared__ unsigned hist[WNB];
    __shared__ unsigned cur[WNB];
    const int w = blockIdx.x;               // 64 windows
    const int t = threadIdx.x;
    const int base = w * 1024;
    if (t < WNB) hist[t] = 0;
    __syncthreads();
    unsigned nch[4];
    for (int j = 0; j < 4; ++j) {
        unsigned c = counts[base + t * 4 + j];
        nch[j] = (c + 3u) >> 2; if (nch[j] > 31u) nch[j] = 31u;
        atomicAdd(&hist[nch[j]], 1u);
    }
    __syncthreads();
    if (t == 0) {
        unsigned run = 0;
        for (int b = 0; b < WNB; ++b) { unsigned v = hist[b]; cur[b] = run; run += v; }
    }
    __syncthreads();
    for (int j = 0; j < 4; ++j) {
        unsigned p = atomicAdd(&cur[nch[j]], 1u);
        sched[base + p] = (unsigned)(base + t * 4 + j);
    }
}

// Phase 1: per-group M + exclusive row scan -> gdesc (1 block, cheap).
__global__ __launch_bounds__(1024) void scan_m_kernel(
    const unsigned* __restrict__ counts, const unsigned* __restrict__ sched,
    unsigned* __restrict__ gdesc)
{
    __shared__ unsigned part[NGROUP];
    const int g = threadIdx.x;
    unsigned M = (counts[sched[g * 64 + 63]] + 3u) >> 2;  // sorted asc -> max
    part[g] = M;
    __syncthreads();
    for (int st = 1; st < NGROUP; st <<= 1) {
        unsigned v = (g >= st) ? part[g - st] : 0u;
        __syncthreads();
        part[g] += v;
        __syncthreads();
    }
    unsigned rowbase = part[g] - M;
    gdesc[g] = (rowbase << 6) | (M << 24);
}

// Phase 2: parallel wbase writer (was the serial tail of R9's group_scan).
__global__ __launch_bounds__(1024) void wbase_kernel(
    const unsigned* __restrict__ sched, const unsigned* __restrict__ gdesc,
    unsigned* __restrict__ wbase)
{
    const int slot = blockIdx.x * 1024 + threadIdx.x;   // 64 blocks
    const unsigned o = sched[slot];
    const unsigned g = (unsigned)slot >> 6, l = (unsigned)slot & 63u;
    wbase[o] = ((gdesc[g] & 0xffffffu) + l) * 4u;
}

// Scatter taps into the interleaved layout.
// Entry: bits[15:0] = (hw<<2)|k  (halfword index into xkh[hw][k]),
//        bits[31:16] = fp16 weight.  r = hw*16 + k*4 + p.
__global__ __launch_bounds__(256) void scatter_v2_kernel(
    const int* __restrict__ sm, const float* __restrict__ iw,
    unsigned* __restrict__ cursor, const unsigned* __restrict__ wbase,
    unsigned* __restrict__ entries2_u32)
{
    int r = blockIdx.x * 256 + threadIdx.x;
    if (r >= TAPS) return;
    int o = sm[r];
    unsigned hw = (unsigned)(r >> 4);
    unsigned k  = (unsigned)((r >> 2) & 3);
    __half h = __float2half_rn(iw[r]);
    unsigned short hb; __builtin_memcpy(&hb, &h, 2);
    unsigned ent = (hw << 2) | k | ((unsigned)hb << 16);
    unsigned idx = atomicAdd(&cursor[o], 1u);
    entries2_u32[wbase[o] + ((idx >> 2) << 8) + (idx & 3u)] = ent;
}

// ================= V2 main kernel: per-k masked fp16 + dot2 =================
// xkh[hw][k] = (idx_mask[hw]==k) ? fp16(x[hw]) : 0  -> the k-check vanishes:
// invalid taps read exactly 0. Entry low16 IS the halfword index. Per entry:
// and+shl addr + ds_read_u16; per pair: 2 v_perm + 1 v_dot2_f32_f16.
// 128 KiB xkh + 16 KiB stg = 144 KiB -> 1 block/CU (16 waves), LDS-pipe bound.
__global__ __launch_bounds__(1024) void unpool_dot_kernel(
    const float* __restrict__ x,
    const int*   __restrict__ idx_mask,
    const unsigned* __restrict__ sched,
    const unsigned* __restrict__ gdesc,
    const uint4* __restrict__ entries2,
    float* __restrict__ out)
{
    __shared__ unsigned short xkh[HW * 4];   // 128 KiB, [hw][k] masked fp16
    __shared__ float stg[GW * 1024];         // 16 KiB

    const int bc = blockIdx.x;
    const float4* xp4 = (const float4*)(x + (size_t)bc * HW);
    const int4*   ip4 = (const int4*)(idx_mask + (size_t)bc * HW);
    uint2* xk2 = (uint2*)xkh;                // one uint2 = 4 halfs = input row

    for (int t = threadIdx.x; t < HW / 4; t += 1024) {
        float4 xv = xp4[t];
        int4   kv = ip4[t];
        float xs[4] = {xv.x, xv.y, xv.z, xv.w};
        int   ks[4] = {kv.x, kv.y, kv.z, kv.w};
        for (int c = 0; c < 4; ++c) {
            __half h = __float2half_rn(xs[c]);
            unsigned short hb; __builtin_memcpy(&hb, &h, 2);
            unsigned k = (unsigned)ks[c] & 3u;
            unsigned sh = ((unsigned)hb) << ((k & 1u) << 4);
            uint2 v;
            v.x = (k & 2u) ? 0u : sh;
            v.y = (k & 2u) ? sh : 0u;
            xk2[t * 4 + c] = v;
        }
    }
    __syncthreads();

    const char* xkb = (const char*)xkh;
    const float4* stg4 = (const float4*)stg;
    float4* op4 = (float4*)(out + (size_t)bc * PLANE);

    const int lane = threadIdx.x & 63;
    const int wid  = threadIdx.x >> 6;

#if __has_builtin(__builtin_amdgcn_perm) && __has_builtin(__builtin_amdgcn_fdot2)
#define PAIR(Ea, Eb) { \
    unsigned ua = *(const unsigned short*)(xkb + (((Ea) & 0xffffu) << 1)); \
    unsigned ub = *(const unsigned short*)(xkb + (((Eb) & 0xffffu) << 1)); \
    unsigned xp_ = __builtin_amdgcn_perm(ub, ua, 0x05040100u); \
    unsigned wp_ = __builtin_amdgcn_perm((Eb), (Ea), 0x07060302u); \
    acc = __builtin_amdgcn_fdot2(as_h2(xp_), as_h2(wp_), acc, false); }
#else
#define PAIR(Ea, Eb) { \
    unsigned ua = *(const unsigned short*)(xkb + (((Ea) & 0xffffu) << 1)); \
    unsigned ub = *(const unsigned short*)(xkb + (((Eb) & 0xffffu) << 1)); \
    acc = fmaf(h2f((unsigned short)((Ea) >> 16)), h2f((unsigned short)ua), acc); \
    acc = fmaf(h2f((unsigned short)((Eb) >> 16)), h2f((unsigned short)ub), acc); }
#endif

    for (int gq = 0; gq < PLANE / 1024 / GW; ++gq) {   // 16 groups of 4 windows
        for (int iw2 = 0; iw2 < GW; ++iw2) {
            const int i = gq * GW + iw2;
            const int s = (wid + i) & 15;
            const int g = i * 16 + s;
            const unsigned gd = gdesc[g];
            const unsigned M  = gd >> 24;
            const uint4* ep = entries2 + (gd & 0xffffffu) + lane;
            float acc = 0.f;
            if (M) {
                uint4 ch = ep[0];
                for (unsigned j = 1; j < M; ++j) {     // prefetch next row
                    uint4 nx = ep[j << 6];
                    PAIR(ch.x, ch.y) PAIR(ch.z, ch.w)
                    ch = nx;
                }
                PAIR(ch.x, ch.y) PAIR(ch.z, ch.w)
            }
            const unsigned oid = sched[g * 64 + lane];
            stg[iw2 * 1024 + (oid & 1023u)] = acc;     // LDS scatter (cheap)
        }
        __syncthreads();
        op4[gq * 1024 + threadIdx.x] = stg4[threadIdx.x]; // full-line stores
        __syncthreads();
    }
#undef PAIR
}

// ================= R7 fallback pipeline (verified, 226 us main) =================

__global__ __launch_bounds__(256) void zero_ws_kernel(
    unsigned* __restrict__ counts, uint4* __restrict__ entries)
{
    int r = blockIdx.x * 256 + threadIdx.x;
    if (r < PLANE)     counts[r]  = 0u;
    if (r < CHUNK_CAP) entries[r] = make_uint4(0u, 0u, 0u, 0u);
}

__global__ __launch_bounds__(1024) void scan_chunks_kernel(
    const unsigned* __restrict__ counts,
    unsigned* __restrict__ desc, unsigned* __restrict__ cursor)
{
    __shared__ unsigned part[1024];
    const int t = threadIdx.x;
    const int base = t * 64;
    unsigned s = 0;
    for (int j = 0; j < 64; ++j) s += (counts[base + j] + 3u) >> 2;
    part[t] = s;
    __syncthreads();
    for (int st = 1; st < 1024; st <<= 1) {
        unsigned v = (t >= st) ? part[t - st] : 0u;
        __syncthreads();
        part[t] += v;
        __syncthreads();
    }
    unsigned run = part[t] - s;
    for (int j = 0; j < 64; ++j) {
        unsigned c   = counts[base + j];
        unsigned nch = (c + 3u) >> 2;
        desc[base + j]   = run | (nch << 24);
        cursor[base + j] = run * 4u;
        run += nch;
    }
}

__global__ __launch_bounds__(256) void scatter_chunks_kernel(
    const int* __restrict__ sm, const float* __restrict__ iw,
    unsigned* __restrict__ cursor, unsigned* __restrict__ entries_u32)
{
    int r = blockIdx.x * 256 + threadIdx.x;
    if (r >= TAPS) return;
    int o = sm[r];
    unsigned hw = (unsigned)(r >> 4);
    unsigned k  = (unsigned)((r >> 2) & 3);
    __half h = __float2half_rn(iw[r]);
    unsigned short hb; __builtin_memcpy(&hb, &h, 2);
    unsigned ent = (hw << 2) | k | ((unsigned)hb << 16);
    unsigned pos = atomicAdd(&cursor[o], 1u);
    entries_u32[pos] = ent;
}

__global__ __launch_bounds__(256) void window_sort_kernel(
    const unsigned* __restrict__ desc, uint2* __restrict__ sched)
{
    __shared__ unsigned hist[WNB];
    __shared__ unsigned cur[WNB];
    const int w = blockIdx.x;
    const int t = threadIdx.x;
    const int base = w * 1024;
    if (t < WNB) hist[t] = 0;
    __syncthreads();
    unsigned d[4], nch[4];
    for (int j = 0; j < 4; ++j) {
        d[j] = desc[base + t * 4 + j];
        nch[j] = d[j] >> 24; if (nch[j] > 31u) nch[j] = 31u;
        atomicAdd(&hist[nch[j]], 1u);
    }
    __syncthreads();
    if (t == 0) {
        unsigned run = 0;
        for (int b = 0; b < WNB; ++b) { unsigned v = hist[b]; cur[b] = run; run += v; }
    }
    __syncthreads();
    for (int j = 0; j < 4; ++j) {
        unsigned p = atomicAdd(&cur[nch[j]], 1u);
        sched[base + p] = make_uint2(d[j], (unsigned)(base + t * 4 + j));
    }
}

__global__ __launch_bounds__(1024) void unpool_staged_kernel(
    const float* __restrict__ x,
    const int*   __restrict__ idx_mask,
    const uint2* __restrict__ sched,
    const uint4* __restrict__ entries,
    float* __restrict__ out)
{
    __shared__ unsigned xk[HW];
    __shared__ float    stg[GW * 1024];

    const int bc = blockIdx.x;
    const float4* xp4 = (const float4*)(x + (size_t)bc * HW);
    const int4*   ip4 = (const int4*)(idx_mask + (size_t)bc * HW);
    uint4* xk4 = (uint4*)xk;

    for (int t = threadIdx.x; t < HW / 4; t += 1024) {
        float4 xv = xp4[t];
        int4   kv = ip4[t];
        uint4 o;
        o.x = (__float_as_uint(xv.x) & ~3u) | ((unsigned)kv.x & 3u);
        o.y = (__float_as_uint(xv.y) & ~3u) | ((unsigned)kv.y & 3u);
        o.z = (__float_as_uint(xv.z) & ~3u) | ((unsigned)kv.z & 3u);
        o.w = (__float_as_uint(xv.w) & ~3u) | ((unsigned)kv.w & 3u);
        xk4[t] = o;
    }
    __syncthreads();

    const char* xkb = (const char*)xk;
    const float4* stg4 = (const float4*)stg;
    float4* op4 = (float4*)(out + (size_t)bc * PLANE);

    const int lane = threadIdx.x & 63;
    const int wid  = threadIdx.x >> 6;

    for (int g = 0; g < PLANE / 1024 / GW; ++g) {
        for (int iw2 = 0; iw2 < GW; ++iw2) {
            const int i = g * GW + iw2;
            const int slot = i * 1024 + (((wid + i) & 15) << 6) + lane;
            const uint2 s = sched[slot];
            const unsigned nch = s.x >> 24;
            const uint4* ep = entries + (s.x & 0xffffffu);
            float acc = 0.f;
            for (unsigned j = 0; j < nch; ++j) {
                uint4 ch = ep[j];
                {   unsigned e = ch.x;
                    unsigned u = *(const unsigned*)(xkb + (e & 0xfffcu));
                    float w = (((u ^ e) & 3u) == 0u) ? h2f((unsigned short)(e >> 16)) : 0.f;
                    acc = fmaf(w, __uint_as_float(u & ~3u), acc); }
                {   unsigned e = ch.y;
                    unsigned u = *(const unsigned*)(xkb + (e & 0xfffcu));
                    float w = (((u ^ e) & 3u) == 0u) ? h2f((unsigned short)(e >> 16)) : 0.f;
                    acc = fmaf(w, __uint_as_float(u & ~3u), acc); }
                {   unsigned e = ch.z;
                    unsigned u = *(const unsigned*)(xkb + (e & 0xfffcu));
                    float w = (((u ^ e) & 3u) == 0u) ? h2f((unsigned short)(e >> 16)) : 0.f;
                    acc = fmaf(w, __uint_as_float(u & ~3u), acc); }
                {   unsigned e = ch.w;
                    unsigned u = *(const unsigned*)(xkb + (e & 0xfffcu));
                    float w = (((u ^ e) & 3u) == 0u) ? h2f((unsigned short)(e >> 16)) : 0.f;
                    acc = fmaf(w, __uint_as_float(u & ~3u), acc); }
            }
            stg[iw2 * 1024 + (s.y & 1023)] = acc;
        }
        __syncthreads();
        op4[g * 1024 + threadIdx.x] = stg4[threadIdx.x];
        __syncthreads();
    }
}

// ================= last-resort fallbacks =================

static __device__ __forceinline__ uint4 sel4(bool c, uint4 a, uint4 b) {
    return make_uint4(c ? a.x : b.x, c ? a.y : b.y, c ? a.z : b.z, c ? a.w : b.w);
}
static __device__ __forceinline__ float2 u2f2(unsigned u) {
    __half2 h; __builtin_memcpy(&h, &u, 4); return __half22float2(h);
}

__global__ __launch_bounds__(256) void compact_table_kernel(
    const int4* __restrict__ sm, const float4* __restrict__ iw, uint4* __restrict__ ct)
{
    int r = blockIdx.x * blockDim.x + threadIdx.x;
    if (r >= HW * K) return;
    int4   s = sm[r];
    float4 w = iw[r];
    uint4 o;
    o.x = ((unsigned)s.x & 0xffffu) | (((unsigned)s.y & 0xffffu) << 16);
    o.y = ((unsigned)s.z & 0xffffu) | (((unsigned)s.w & 0xffffu) << 16);
    __half2 h01 = __floats2half2_rn(w.x, w.y);
    __half2 h23 = __floats2half2_rn(w.z, w.w);
    __builtin_memcpy(&o.z, &h01, 4);
    __builtin_memcpy(&o.w, &h23, 4);
    ct[r] = o;
}

__global__ __launch_bounds__(BLOCK) void unpool_lds2_kernel(
    const float* __restrict__ x,
    const int*   __restrict__ idx_mask,
    const uint4* __restrict__ ct,
    float* __restrict__ out)
{
    __shared__ float acc[QUARTER];

    const int bc    = blockIdx.x >> 2;
    const int q     = blockIdx.x & 3;
    const int qbase = q * QUARTER;

    float4* acc4 = (float4*)acc;
    for (int t = threadIdx.x; t < QUARTER / 4; t += BLOCK)
        acc4[t] = make_float4(0.f, 0.f, 0.f, 0.f);
    __syncthreads();

    const float* xp = x + (size_t)bc * HW;
    const int*   ip = idx_mask + (size_t)bc * HW;

    for (int hw = threadIdx.x; hw < HW; hw += BLOCK) {
        float xv = xp[hw];
        int   k  = ip[hw];
        const uint4* c = ct + (hw << 2);
        uint4 r0 = c[0], r1 = c[1], r2 = c[2], r3 = c[3];
        uint4 rl = sel4(k & 1, r1, r0);
        uint4 rh = sel4(k & 1, r3, r2);
        uint4 r  = sel4(k & 2, rh, rl);

        int i0 = r.x & 0xffff, i1 = (int)(r.x >> 16);
        int i2 = r.y & 0xffff, i3 = (int)(r.y >> 16);
        float2 w01 = u2f2(r.z);
        float2 w23 = u2f2(r.w);

        int a;
        a = i0 - qbase; if ((unsigned)a < (unsigned)QUARTER) atomicAdd(&acc[a], w01.x * xv);
        a = i1 - qbase; if ((unsigned)a < (unsigned)QUARTER) atomicAdd(&acc[a], w01.y * xv);
        a = i2 - qbase; if ((unsigned)a < (unsigned)QUARTER) atomicAdd(&acc[a], w23.x * xv);
        a = i3 - qbase; if ((unsigned)a < (unsigned)QUARTER) atomicAdd(&acc[a], w23.y * xv);
    }
    __syncthreads();

    float4* op4 = (float4*)(out + (size_t)bc * PLANE + qbase);
    for (int t = threadIdx.x; t < QUARTER / 4; t += BLOCK)
        op4[t] = acc4[t];
}

__global__ __launch_bounds__(256) void unpool_lds_fallback_kernel(
    const float* __restrict__ x,
    const int*   __restrict__ idx_mask,
    const int4*  __restrict__ sample_map,
    const float4* __restrict__ interp_w,
    float* __restrict__ out)
{
    __shared__ float acc[QUARTER];
    const int bc    = blockIdx.x >> 2;
    const int q     = blockIdx.x & 3;
    const int qbase = q * QUARTER;
    float4* acc4 = (float4*)acc;
    for (int t = threadIdx.x; t < QUARTER / 4; t += 256)
        acc4[t] = make_float4(0.f, 0.f, 0.f, 0.f);
    __syncthreads();
    const float* xp = x + (size_t)bc * HW;
    const int*   ip = idx_mask + (size_t)bc * HW;
    for (int hw = threadIdx.x; hw < HW; hw += 256) {
        float xv = xp[hw];
        int   k  = ip[hw];
        int row = hw * K + k;
        int4   sel = sample_map[row];
        float4 w   = interp_w[row];
        int a;
        a = sel.x - qbase; if ((unsigned)a < (unsigned)QUARTER) atomicAdd(&acc[a], w.x * xv);
        a = sel.y - qbase; if ((unsigned)a < (unsigned)QUARTER) atomicAdd(&acc[a], w.y * xv);
        a = sel.z - qbase; if ((unsigned)a < (unsigned)QUARTER) atomicAdd(&acc[a], w.z * xv);
        a = sel.w - qbase; if ((unsigned)a < (unsigned)QUARTER) atomicAdd(&acc[a], w.w * xv);
    }
    __syncthreads();
    float4* op4 = (float4*)(out + (size_t)bc * PLANE + qbase);
    for (int t = threadIdx.x; t < QUARTER / 4; t += 256)
        op4[t] = acc4[t];
}

static void launch_r7_pipeline(const float* x, const int* idx_mask,
                               const int* sample_map, const float* interp_w,
                               float* out, void* d_ws, hipStream_t stream) {
    unsigned* desc    = (unsigned*)d_ws;
    unsigned* cursor  = desc + PLANE;
    unsigned* counts  = cursor + PLANE;
    uint2*    sched   = (uint2*)(counts + PLANE);
    uint4*    entries = (uint4*)(counts + PLANE + 2 * PLANE);

    zero_ws_kernel<<<(CHUNK_CAP + 255) / 256, 256, 0, stream>>>(counts, entries);
    hist_kernel<<<TAPS / 256, 256, 0, stream>>>(sample_map, counts);
    scan_chunks_kernel<<<1, 1024, 0, stream>>>(counts, desc, cursor);
    scatter_chunks_kernel<<<TAPS / 256, 256, 0, stream>>>(
        sample_map, interp_w, cursor, (unsigned*)entries);
    window_sort_kernel<<<PLANE / 1024, 256, 0, stream>>>(desc, sched);
    unpool_staged_kernel<<<B * C, 1024, 0, stream>>>(x, idx_mask, sched, entries, out);
}

extern "C" void kernel_launch(void* const* d_in, const int* in_sizes, int n_in,
                              void* d_out, int out_size, void* d_ws, size_t ws_size,
                              hipStream_t stream) {
    const float*  x          = (const float*)d_in[0];
    const int*    idx_mask   = (const int*)d_in[1];
    const int*    sample_map = (const int*)d_in[2];
    const float*  interp_w   = (const float*)d_in[3];
    float* out = (float*)d_out;

    if (ws_size >= WS_V2_BYTES) {
        unsigned* counts   = (unsigned*)d_ws;
        unsigned* cursor   = counts + PLANE;
        unsigned* sched    = cursor + PLANE;
        unsigned* wbase    = sched + PLANE;
        unsigned* gdesc    = wbase + PLANE;
        uint4*    entries2 = (uint4*)(gdesc + 2048);

        zero_v2_kernel<<<(E2CAP + 255) / 256, 256, 0, stream>>>(counts, cursor, entries2);
        hist_kernel<<<TAPS / 256, 256, 0, stream>>>(sample_map, counts);
        window_sort_v2_kernel<<<PLANE / 1024, 256, 0, stream>>>(counts, sched);
        scan_m_kernel<<<1, NGROUP, 0, stream>>>(counts, sched, gdesc);
        wbase_kernel<<<PLANE / 1024, 1024, 0, stream>>>(sched, gdesc, wbase);
        scatter_v2_kernel<<<TAPS / 256, 256, 0, stream>>>(
            sample_map, interp_w, cursor, wbase, (unsigned*)entries2);
        unpool_dot_kernel<<<B * C, 1024, 0, stream>>>(
            x, idx_mask, sched, gdesc, entries2, out);
        // Safety net: if the 144 KiB-LDS kernel is rejected at launch, run the
        // fully verified R7 pipeline instead (ws is large enough for both).
        if (hipGetLastError() != hipSuccess) {
            launch_r7_pipeline(x, idx_mask, sample_map, interp_w, out, d_ws, stream);
        }
    } else if (ws_size >= WS_SORT_BYTES) {
        launch_r7_pipeline(x, idx_mask, sample_map, interp_w, out, d_ws, stream);
    } else if (ws_size >= TABLE_BYTES) {
        uint4* ct = (uint4*)d_ws;
        compact_table_kernel<<<(HW * K + 255) / 256, 256, 0, stream>>>(
            (const int4*)sample_map, (const float4*)interp_w, ct);
        unpool_lds2_kernel<<<B * C * NQ, BLOCK, 0, stream>>>(
            x, idx_mask, ct, out);
    } else {
        unpool_lds_fallback_kernel<<<B * C * NQ, 256, 0, stream>>>(
            x, idx_mask, (const int4*)sample_map, (const float4*)interp_w, out);
    }
}

// Round 11
// 506.541 us; speedup vs baseline: 1.2445x; 1.2445x over previous
//
#include <hip/hip_runtime.h>
#include <hip/hip_fp16.h>

// Problem constants (from reference setup_inputs)
constexpr int B  = 16;
constexpr int C  = 64;
constexpr int OH = 128;
constexpr int OW = 128;
constexpr int HW = OH * OW;                 // 16384 inputs per (b,c) plane
constexpr int K  = 4;
constexpr int P  = 4;
constexpr int TAPS = HW * K * P;            // 262144 static taps
constexpr int OUT_H = 256;
constexpr int OUT_W = 256;
constexpr int PLANE = OUT_H * OUT_W;        // 65536 outputs per (b,c) plane
constexpr int NQ = 4;                       // quarters (fallback path)
constexpr int QUARTER = PLANE / NQ;
constexpr int BLOCK = 512;
constexpr size_t TABLE_BYTES = (size_t)HW * K * 16;  // 1 MiB compact table (fallback)

constexpr int GW = 4;                       // windows per staging group
constexpr int NGROUP = PLANE / 64;          // 1024 64-slot schedule groups

// ---- V2 (grouped/interleaved) workspace, u32 slots ----
//   counts : PLANE
//   cursor : PLANE
//   sched  : PLANE   (out_id per sorted slot)
//   wbase  : PLANE   (per-output u32 write base into entries2)
//   gdesc  : 2048    (uint4_base | M<<24, 1024 used; uint4_base = rowbase*64)
//   entries2: E2CAP uint4 chunks, lane-interleaved per group
//   Group g: chunk-row j of lane l at uint4 index base + j*64 + l.
//   M is padded to EVEN (R11: row-pair unroll); pad rows are zeroed ->
//   fp16 weight bits 0 -> contribute exactly 0.
constexpr int E2CAP = 229376;               // row budget 3584 vs ~2.6K worst
constexpr size_t WS_V2_BYTES = ((size_t)PLANE * 4 + 2048) * 4 + (size_t)E2CAP * 16;

// ---- R7 (sorted+staged) workspace ----
constexpr int CHUNK_CAP = 114688;
constexpr size_t WS_SORT_BYTES = ((size_t)PLANE * 5) * 4 + (size_t)CHUNK_CAP * 16; // 3.0 MiB

static __device__ __forceinline__ float h2f(unsigned short u) {
    __half h; __builtin_memcpy(&h, &u, 2); return __half2float(h);
}

// ================= shared pre-pass =================

__global__ __launch_bounds__(256) void hist_kernel(
    const int* __restrict__ sm, unsigned* __restrict__ counts)
{
    int r = blockIdx.x * 256 + threadIdx.x;
    if (r < TAPS) atomicAdd(&counts[sm[r]], 1u);
}

// ================= V2 pre-pass =================

__global__ __launch_bounds__(256) void zero_v2_kernel(
    unsigned* __restrict__ counts, unsigned* __restrict__ cursor,
    uint4* __restrict__ entries2)
{
    int r = blockIdx.x * 256 + threadIdx.x;
    if (r < PLANE) { counts[r] = 0u; cursor[r] = 0u; }
    if (r < E2CAP) entries2[r] = make_uint4(0u, 0u, 0u, 0u);
}

// Window-local counting sort by nch=ceil(counts/4), ascending.
constexpr int WNB = 32;
__global__ __launch_bounds__(256) void window_sort_v2_kernel(
    const unsigned* __restrict__ counts, unsigned* __restrict__ sched)
{
    __shared__ unsigned hist[WNB];
    __shared__ unsigned cur[WNB];
    const int w = blockIdx.x;               // 64 windows
    const int t = threadIdx.x;
    const int base = w * 1024;
    if (t < WNB) hist[t] = 0;
    __syncthreads();
    unsigned nch[4];
    for (int j = 0; j < 4; ++j) {
        unsigned c = counts[base + t * 4 + j];
        nch[j] = (c + 3u) >> 2; if (nch[j] > 31u) nch[j] = 31u;
        atomicAdd(&hist[nch[j]], 1u);
    }
    __syncthreads();
    if (t == 0) {
        unsigned run = 0;
        for (int b = 0; b < WNB; ++b) { unsigned v = hist[b]; cur[b] = run; run += v; }
    }
    __syncthreads();
    for (int j = 0; j < 4; ++j) {
        unsigned p = atomicAdd(&cur[nch[j]], 1u);
        sched[base + p] = (unsigned)(base + t * 4 + j);
    }
}

// Phase 1: per-group M (max nch, padded to even) + exclusive row scan.
__global__ __launch_bounds__(1024) void scan_m_kernel(
    const unsigned* __restrict__ counts, const unsigned* __restrict__ sched,
    unsigned* __restrict__ gdesc)
{
    __shared__ unsigned part[NGROUP];
    const int g = threadIdx.x;
    unsigned M = (counts[sched[g * 64 + 63]] + 3u) >> 2;  // sorted asc -> max
    if (M > 31u) M = 31u;                    // mirror sort clamp
    M = (M + 1u) & ~1u;                      // pad to even for row-pair unroll
    part[g] = M;
    __syncthreads();
    for (int st = 1; st < NGROUP; st <<= 1) {
        unsigned v = (g >= st) ? part[g - st] : 0u;
        __syncthreads();
        part[g] += v;
        __syncthreads();
    }
    unsigned rowbase = part[g] - M;
    gdesc[g] = (rowbase << 6) | (M << 24);
}

// Phase 2: parallel wbase writer.
__global__ __launch_bounds__(1024) void wbase_kernel(
    const unsigned* __restrict__ sched, const unsigned* __restrict__ gdesc,
    unsigned* __restrict__ wbase)
{
    const int slot = blockIdx.x * 1024 + threadIdx.x;   // 64 blocks
    const unsigned o = sched[slot];
    const unsigned g = (unsigned)slot >> 6, l = (unsigned)slot & 63u;
    wbase[o] = ((gdesc[g] & 0xffffffu) + l) * 4u;
}

// Scatter taps into the interleaved layout.
// Entry: bits[1:0]=k, bits[15:2]=hw<<2 (LDS byte addr), bits[31:16]=fp16 w.
__global__ __launch_bounds__(256) void scatter_v2_kernel(
    const int* __restrict__ sm, const float* __restrict__ iw,
    unsigned* __restrict__ cursor, const unsigned* __restrict__ wbase,
    unsigned* __restrict__ entries2_u32)
{
    int r = blockIdx.x * 256 + threadIdx.x;
    if (r >= TAPS) return;
    int o = sm[r];
    unsigned hw = (unsigned)(r >> 4);
    unsigned k  = (unsigned)((r >> 2) & 3);
    __half h = __float2half_rn(iw[r]);
    unsigned short hb; __builtin_memcpy(&hb, &h, 2);
    unsigned ent = (hw << 2) | k | ((unsigned)hb << 16);
    unsigned idx = atomicAdd(&cursor[o], 1u);
    entries2_u32[wbase[o] + ((idx >> 2) << 8) + (idx & 3u)] = ent;
}

// ================= V2 main kernel (R11: row-pair unroll) =================
// R9 structure (80 KiB LDS, 2 blocks/CU = 32 waves, verified 210us) +
// doubled memory-level parallelism: M even -> process 2 rows/iteration with
// explicit read-phase (8 back-to-back ds_read_b32) then compute-phase
// (8 check+fma). 2 VMEM row prefetches/iteration. Targets overlap of the
// VALU (~97us) and LDS (~113us) pipes that R9 ran back-to-back.
__global__ __launch_bounds__(1024) void unpool_grouped2_kernel(
    const float* __restrict__ x,
    const int*   __restrict__ idx_mask,
    const unsigned* __restrict__ sched,
    const unsigned* __restrict__ gdesc,
    const uint4* __restrict__ entries2,
    float* __restrict__ out)
{
    __shared__ unsigned xk[HW];              // 64 KiB: (bits(x)&~3)|k
    __shared__ float    stg[GW * 1024];      // 16 KiB -> 80 KiB, 2 blocks/CU

    const int bc = blockIdx.x;
    const float4* xp4 = (const float4*)(x + (size_t)bc * HW);
    const int4*   ip4 = (const int4*)(idx_mask + (size_t)bc * HW);
    uint4* xk4 = (uint4*)xk;

    for (int t = threadIdx.x; t < HW / 4; t += 1024) {
        float4 xv = xp4[t];
        int4   kv = ip4[t];
        uint4 o;
        o.x = (__float_as_uint(xv.x) & ~3u) | ((unsigned)kv.x & 3u);
        o.y = (__float_as_uint(xv.y) & ~3u) | ((unsigned)kv.y & 3u);
        o.z = (__float_as_uint(xv.z) & ~3u) | ((unsigned)kv.z & 3u);
        o.w = (__float_as_uint(xv.w) & ~3u) | ((unsigned)kv.w & 3u);
        xk4[t] = o;
    }
    __syncthreads();

    const char* xkb = (const char*)xk;
    const float4* stg4 = (const float4*)stg;
    float4* op4 = (float4*)(out + (size_t)bc * PLANE);

    const int lane = threadIdx.x & 63;
    const int wid  = threadIdx.x >> 6;

#define LDX(E) (*(const unsigned*)(xkb + ((E) & 0xfffcu)))
#define ACC1(E, U) { \
    float w_ = ((((U) ^ (E)) & 3u) == 0u) ? h2f((unsigned short)((E) >> 16)) : 0.f; \
    acc = fmaf(w_, __uint_as_float(U), acc); }

    for (int gq = 0; gq < PLANE / 1024 / GW; ++gq) {   // 16 groups of 4 windows
        for (int iw2 = 0; iw2 < GW; ++iw2) {
            const int i = gq * GW + iw2;
            const int s = (wid + i) & 15;
            const int g = i * 16 + s;
            const unsigned gd = gdesc[g];
            const unsigned M  = gd >> 24;              // even (or 0)
            const uint4* ep = entries2 + (gd & 0xffffffu) + lane;
            float acc = 0.f;
            if (M) {
                uint4 a = ep[0];
                uint4 b = ep[64];
                for (unsigned j = 2; j < M; j += 2) {
                    uint4 na = ep[j << 6];             // prefetch next row pair
                    uint4 nb = ep[(j + 1) << 6];
                    // read phase: 8 independent ds_reads
                    unsigned u0 = LDX(a.x), u1 = LDX(a.y), u2 = LDX(a.z), u3 = LDX(a.w);
                    unsigned v0 = LDX(b.x), v1 = LDX(b.y), v2 = LDX(b.z), v3 = LDX(b.w);
                    // compute phase
                    ACC1(a.x, u0) ACC1(a.y, u1) ACC1(a.z, u2) ACC1(a.w, u3)
                    ACC1(b.x, v0) ACC1(b.y, v1) ACC1(b.z, v2) ACC1(b.w, v3)
                    a = na; b = nb;
                }
                {   // epilogue pair
                    unsigned u0 = LDX(a.x), u1 = LDX(a.y), u2 = LDX(a.z), u3 = LDX(a.w);
                    unsigned v0 = LDX(b.x), v1 = LDX(b.y), v2 = LDX(b.z), v3 = LDX(b.w);
                    ACC1(a.x, u0) ACC1(a.y, u1) ACC1(a.z, u2) ACC1(a.w, u3)
                    ACC1(b.x, v0) ACC1(b.y, v1) ACC1(b.z, v2) ACC1(b.w, v3)
                }
            }
            const unsigned oid = sched[g * 64 + lane];
            stg[iw2 * 1024 + (oid & 1023u)] = acc;     // LDS scatter (cheap)
        }
        __syncthreads();
        op4[gq * 1024 + threadIdx.x] = stg4[threadIdx.x]; // full-line stores
        __syncthreads();
    }
#undef LDX
#undef ACC1
}

// ================= R7 fallback pipeline (verified, 226 us main) =================

__global__ __launch_bounds__(256) void zero_ws_kernel(
    unsigned* __restrict__ counts, uint4* __restrict__ entries)
{
    int r = blockIdx.x * 256 + threadIdx.x;
    if (r < PLANE)     counts[r]  = 0u;
    if (r < CHUNK_CAP) entries[r] = make_uint4(0u, 0u, 0u, 0u);
}

__global__ __launch_bounds__(1024) void scan_chunks_kernel(
    const unsigned* __restrict__ counts,
    unsigned* __restrict__ desc, unsigned* __restrict__ cursor)
{
    __shared__ unsigned part[1024];
    const int t = threadIdx.x;
    const int base = t * 64;
    unsigned s = 0;
    for (int j = 0; j < 64; ++j) s += (counts[base + j] + 3u) >> 2;
    part[t] = s;
    __syncthreads();
    for (int st = 1; st < 1024; st <<= 1) {
        unsigned v = (t >= st) ? part[t - st] : 0u;
        __syncthreads();
        part[t] += v;
        __syncthreads();
    }
    unsigned run = part[t] - s;
    for (int j = 0; j < 64; ++j) {
        unsigned c   = counts[base + j];
        unsigned nch = (c + 3u) >> 2;
        desc[base + j]   = run | (nch << 24);
        cursor[base + j] = run * 4u;
        run += nch;
    }
}

__global__ __launch_bounds__(256) void scatter_chunks_kernel(
    const int* __restrict__ sm, const float* __restrict__ iw,
    unsigned* __restrict__ cursor, unsigned* __restrict__ entries_u32)
{
    int r = blockIdx.x * 256 + threadIdx.x;
    if (r >= TAPS) return;
    int o = sm[r];
    unsigned hw = (unsigned)(r >> 4);
    unsigned k  = (unsigned)((r >> 2) & 3);
    __half h = __float2half_rn(iw[r]);
    unsigned short hb; __builtin_memcpy(&hb, &h, 2);
    unsigned ent = (hw << 2) | k | ((unsigned)hb << 16);
    unsigned pos = atomicAdd(&cursor[o], 1u);
    entries_u32[pos] = ent;
}

__global__ __launch_bounds__(256) void window_sort_kernel(
    const unsigned* __restrict__ desc, uint2* __restrict__ sched)
{
    __shared__ unsigned hist[WNB];
    __shared__ unsigned cur[WNB];
    const int w = blockIdx.x;
    const int t = threadIdx.x;
    const int base = w * 1024;
    if (t < WNB) hist[t] = 0;
    __syncthreads();
    unsigned d[4], nch[4];
    for (int j = 0; j < 4; ++j) {
        d[j] = desc[base + t * 4 + j];
        nch[j] = d[j] >> 24; if (nch[j] > 31u) nch[j] = 31u;
        atomicAdd(&hist[nch[j]], 1u);
    }
    __syncthreads();
    if (t == 0) {
        unsigned run = 0;
        for (int b = 0; b < WNB; ++b) { unsigned v = hist[b]; cur[b] = run; run += v; }
    }
    __syncthreads();
    for (int j = 0; j < 4; ++j) {
        unsigned p = atomicAdd(&cur[nch[j]], 1u);
        sched[base + p] = make_uint2(d[j], (unsigned)(base + t * 4 + j));
    }
}

__global__ __launch_bounds__(1024) void unpool_staged_kernel(
    const float* __restrict__ x,
    const int*   __restrict__ idx_mask,
    const uint2* __restrict__ sched,
    const uint4* __restrict__ entries,
    float* __restrict__ out)
{
    __shared__ unsigned xk[HW];
    __shared__ float    stg[GW * 1024];

    const int bc = blockIdx.x;
    const float4* xp4 = (const float4*)(x + (size_t)bc * HW);
    const int4*   ip4 = (const int4*)(idx_mask + (size_t)bc * HW);
    uint4* xk4 = (uint4*)xk;

    for (int t = threadIdx.x; t < HW / 4; t += 1024) {
        float4 xv = xp4[t];
        int4   kv = ip4[t];
        uint4 o;
        o.x = (__float_as_uint(xv.x) & ~3u) | ((unsigned)kv.x & 3u);
        o.y = (__float_as_uint(xv.y) & ~3u) | ((unsigned)kv.y & 3u);
        o.z = (__float_as_uint(xv.z) & ~3u) | ((unsigned)kv.z & 3u);
        o.w = (__float_as_uint(xv.w) & ~3u) | ((unsigned)kv.w & 3u);
        xk4[t] = o;
    }
    __syncthreads();

    const char* xkb = (const char*)xk;
    const float4* stg4 = (const float4*)stg;
    float4* op4 = (float4*)(out + (size_t)bc * PLANE);

    const int lane = threadIdx.x & 63;
    const int wid  = threadIdx.x >> 6;

    for (int g = 0; g < PLANE / 1024 / GW; ++g) {
        for (int iw2 = 0; iw2 < GW; ++iw2) {
            const int i = g * GW + iw2;
            const int slot = i * 1024 + (((wid + i) & 15) << 6) + lane;
            const uint2 s = sched[slot];
            const unsigned nch = s.x >> 24;
            const uint4* ep = entries + (s.x & 0xffffffu);
            float acc = 0.f;
            for (unsigned j = 0; j < nch; ++j) {
                uint4 ch = ep[j];
                {   unsigned e = ch.x;
                    unsigned u = *(const unsigned*)(xkb + (e & 0xfffcu));
                    float w = (((u ^ e) & 3u) == 0u) ? h2f((unsigned short)(e >> 16)) : 0.f;
                    acc = fmaf(w, __uint_as_float(u & ~3u), acc); }
                {   unsigned e = ch.y;
                    unsigned u = *(const unsigned*)(xkb + (e & 0xfffcu));
                    float w = (((u ^ e) & 3u) == 0u) ? h2f((unsigned short)(e >> 16)) : 0.f;
                    acc = fmaf(w, __uint_as_float(u & ~3u), acc); }
                {   unsigned e = ch.z;
                    unsigned u = *(const unsigned*)(xkb + (e & 0xfffcu));
                    float w = (((u ^ e) & 3u) == 0u) ? h2f((unsigned short)(e >> 16)) : 0.f;
                    acc = fmaf(w, __uint_as_float(u & ~3u), acc); }
                {   unsigned e = ch.w;
                    unsigned u = *(const unsigned*)(xkb + (e & 0xfffcu));
                    float w = (((u ^ e) & 3u) == 0u) ? h2f((unsigned short)(e >> 16)) : 0.f;
                    acc = fmaf(w, __uint_as_float(u & ~3u), acc); }
            }
            stg[iw2 * 1024 + (s.y & 1023)] = acc;
        }
        __syncthreads();
        op4[g * 1024 + threadIdx.x] = stg4[threadIdx.x];
        __syncthreads();
    }
}

// ================= last-resort fallbacks =================

static __device__ __forceinline__ uint4 sel4(bool c, uint4 a, uint4 b) {
    return make_uint4(c ? a.x : b.x, c ? a.y : b.y, c ? a.z : b.z, c ? a.w : b.w);
}
static __device__ __forceinline__ float2 u2f2(unsigned u) {
    __half2 h; __builtin_memcpy(&h, &u, 4); return __half22float2(h);
}

__global__ __launch_bounds__(256) void compact_table_kernel(
    const int4* __restrict__ sm, const float4* __restrict__ iw, uint4* __restrict__ ct)
{
    int r = blockIdx.x * blockDim.x + threadIdx.x;
    if (r >= HW * K) return;
    int4   s = sm[r];
    float4 w = iw[r];
    uint4 o;
    o.x = ((unsigned)s.x & 0xffffu) | (((unsigned)s.y & 0xffffu) << 16);
    o.y = ((unsigned)s.z & 0xffffu) | (((unsigned)s.w & 0xffffu) << 16);
    __half2 h01 = __floats2half2_rn(w.x, w.y);
    __half2 h23 = __floats2half2_rn(w.z, w.w);
    __builtin_memcpy(&o.z, &h01, 4);
    __builtin_memcpy(&o.w, &h23, 4);
    ct[r] = o;
}

__global__ __launch_bounds__(BLOCK) void unpool_lds2_kernel(
    const float* __restrict__ x,
    const int*   __restrict__ idx_mask,
    const uint4* __restrict__ ct,
    float* __restrict__ out)
{
    __shared__ float acc[QUARTER];

    const int bc    = blockIdx.x >> 2;
    const int q     = blockIdx.x & 3;
    const int qbase = q * QUARTER;

    float4* acc4 = (float4*)acc;
    for (int t = threadIdx.x; t < QUARTER / 4; t += BLOCK)
        acc4[t] = make_float4(0.f, 0.f, 0.f, 0.f);
    __syncthreads();

    const float* xp = x + (size_t)bc * HW;
    const int*   ip = idx_mask + (size_t)bc * HW;

    for (int hw = threadIdx.x; hw < HW; hw += BLOCK) {
        float xv = xp[hw];
        int   k  = ip[hw];
        const uint4* c = ct + (hw << 2);
        uint4 r0 = c[0], r1 = c[1], r2 = c[2], r3 = c[3];
        uint4 rl = sel4(k & 1, r1, r0);
        uint4 rh = sel4(k & 1, r3, r2);
        uint4 r  = sel4(k & 2, rh, rl);

        int i0 = r.x & 0xffff, i1 = (int)(r.x >> 16);
        int i2 = r.y & 0xffff, i3 = (int)(r.y >> 16);
        float2 w01 = u2f2(r.z);
        float2 w23 = u2f2(r.w);

        int a;
        a = i0 - qbase; if ((unsigned)a < (unsigned)QUARTER) atomicAdd(&acc[a], w01.x * xv);
        a = i1 - qbase; if ((unsigned)a < (unsigned)QUARTER) atomicAdd(&acc[a], w01.y * xv);
        a = i2 - qbase; if ((unsigned)a < (unsigned)QUARTER) atomicAdd(&acc[a], w23.x * xv);
        a = i3 - qbase; if ((unsigned)a < (unsigned)QUARTER) atomicAdd(&acc[a], w23.y * xv);
    }
    __syncthreads();

    float4* op4 = (float4*)(out + (size_t)bc * PLANE + qbase);
    for (int t = threadIdx.x; t < QUARTER / 4; t += BLOCK)
        op4[t] = acc4[t];
}

__global__ __launch_bounds__(256) void unpool_lds_fallback_kernel(
    const float* __restrict__ x,
    const int*   __restrict__ idx_mask,
    const int4*  __restrict__ sample_map,
    const float4* __restrict__ interp_w,
    float* __restrict__ out)
{
    __shared__ float acc[QUARTER];
    const int bc    = blockIdx.x >> 2;
    const int q     = blockIdx.x & 3;
    const int qbase = q * QUARTER;
    float4* acc4 = (float4*)acc;
    for (int t = threadIdx.x; t < QUARTER / 4; t += 256)
        acc4[t] = make_float4(0.f, 0.f, 0.f, 0.f);
    __syncthreads();
    const float* xp = x + (size_t)bc * HW;
    const int*   ip = idx_mask + (size_t)bc * HW;
    for (int hw = threadIdx.x; hw < HW; hw += 256) {
        float xv = xp[hw];
        int   k  = ip[hw];
        int row = hw * K + k;
        int4   sel = sample_map[row];
        float4 w   = interp_w[row];
        int a;
        a = sel.x - qbase; if ((unsigned)a < (unsigned)QUARTER) atomicAdd(&acc[a], w.x * xv);
        a = sel.y - qbase; if ((unsigned)a < (unsigned)QUARTER) atomicAdd(&acc[a], w.y * xv);
        a = sel.z - qbase; if ((unsigned)a < (unsigned)QUARTER) atomicAdd(&acc[a], w.z * xv);
        a = sel.w - qbase; if ((unsigned)a < (unsigned)QUARTER) atomicAdd(&acc[a], w.w * xv);
    }
    __syncthreads();
    float4* op4 = (float4*)(out + (size_t)bc * PLANE + qbase);
    for (int t = threadIdx.x; t < QUARTER / 4; t += 256)
        op4[t] = acc4[t];
}

extern "C" void kernel_launch(void* const* d_in, const int* in_sizes, int n_in,
                              void* d_out, int out_size, void* d_ws, size_t ws_size,
                              hipStream_t stream) {
    const float*  x          = (const float*)d_in[0];
    const int*    idx_mask   = (const int*)d_in[1];
    const int*    sample_map = (const int*)d_in[2];
    const float*  interp_w   = (const float*)d_in[3];
    float* out = (float*)d_out;

    if (ws_size >= WS_V2_BYTES) {
        unsigned* counts   = (unsigned*)d_ws;
        unsigned* cursor   = counts + PLANE;
        unsigned* sched    = cursor + PLANE;
        unsigned* wbase    = sched + PLANE;
        unsigned* gdesc    = wbase + PLANE;
        uint4*    entries2 = (uint4*)(gdesc + 2048);

        zero_v2_kernel<<<(E2CAP + 255) / 256, 256, 0, stream>>>(counts, cursor, entries2);
        hist_kernel<<<TAPS / 256, 256, 0, stream>>>(sample_map, counts);
        window_sort_v2_kernel<<<PLANE / 1024, 256, 0, stream>>>(counts, sched);
        scan_m_kernel<<<1, NGROUP, 0, stream>>>(counts, sched, gdesc);
        wbase_kernel<<<PLANE / 1024, 1024, 0, stream>>>(sched, gdesc, wbase);
        scatter_v2_kernel<<<TAPS / 256, 256, 0, stream>>>(
            sample_map, interp_w, cursor, wbase, (unsigned*)entries2);
        unpool_grouped2_kernel<<<B * C, 1024, 0, stream>>>(
            x, idx_mask, sched, gdesc, entries2, out);
    } else if (ws_size >= WS_SORT_BYTES) {
        unsigned* desc    = (unsigned*)d_ws;
        unsigned* cursor  = desc + PLANE;
        unsigned* counts  = cursor + PLANE;
        uint2*    sched   = (uint2*)(counts + PLANE);
        uint4*    entries = (uint4*)(counts + PLANE + 2 * PLANE);

        zero_ws_kernel<<<(CHUNK_CAP + 255) / 256, 256, 0, stream>>>(counts, entries);
        hist_kernel<<<TAPS / 256, 256, 0, stream>>>(sample_map, counts);
        scan_chunks_kernel<<<1, 1024, 0, stream>>>(counts, desc, cursor);
        scatter_chunks_kernel<<<TAPS / 256, 256, 0, stream>>>(
            sample_map, interp_w, cursor, (unsigned*)entries);
        window_sort_kernel<<<PLANE / 1024, 256, 0, stream>>>(desc, sched);
        unpool_staged_kernel<<<B * C, 1024, 0, stream>>>(x, idx_mask, sched, entries, out);
    } else if (ws_size >= TABLE_BYTES) {
        uint4* ct = (uint4*)d_ws;
        compact_table_kernel<<<(HW * K + 255) / 256, 256, 0, stream>>>(
            (const int4*)sample_map, (const float4*)interp_w, ct);
        unpool_lds2_kernel<<<B * C * NQ, BLOCK, 0, stream>>>(
            x, idx_mask, ct, out);
    } else {
        unpool_lds_fallback_kernel<<<B * C * NQ, 256, 0, stream>>>(
            x, idx_mask, (const int4*)sample_map, (const float4*)interp_w, out);
    }
}